// Round 1
// baseline (101.986 us; speedup 1.0000x reference)
//
#include <hip/hip_runtime.h>
#include <hip/hip_bf16.h>

typedef __bf16 bf16x8 __attribute__((ext_vector_type(8)));
typedef float f32x4 __attribute__((ext_vector_type(4)));

constexpr int NE   = 16;
constexpr int NB   = 4096;
constexpr int INF  = 1024;
constexpr int OUTF = 1024;
constexpr int KTOT = 2048;          // concat of [logits | prior]
constexpr int BM = 128, BN = 128, BK = 64;
constexpr int NSTEP  = KTOT / BK;   // 32
constexpr int ABYTES = BM * BK * 2; // 16 KiB per bf16 tile buffer
constexpr int MAXMT  = NB / BM;     // 32 worst-case M-tiles per expert

__device__ __forceinline__ unsigned short f2bf(float f) {
  union { float f; unsigned int u; } x{f};
  unsigned int r = x.u + 0x7fffu + ((x.u >> 16) & 1u);   // RTNE
  return (unsigned short)(r >> 16);
}

__global__ void route_init_kernel(int* counts) {
  if (threadIdx.x < NE) counts[threadIdx.x] = 0;
}

__global__ void route_kernel(const int* __restrict__ eidx, int* counts, int* rows) {
  int i = blockIdx.x * blockDim.x + threadIdx.x;
  if (i < NB) {
    int e = eidx[i];
    int slot = atomicAdd(&counts[e], 1);
    rows[e * NB + slot] = i;
  }
}

__global__ __launch_bounds__(256, 2) void ens_gemm_kernel(
    const float* __restrict__ X0,    // logits     [NB, INF]
    const float* __restrict__ X1,    // prior      [NB, INF]
    const float* __restrict__ W0,    // [NE, OUTF, INF]
    const float* __restrict__ B0,    // [NE, OUTF]
    const float* __restrict__ W1,
    const float* __restrict__ B1,
    const int* __restrict__ counts,
    const int* __restrict__ rows,
    float* __restrict__ out)         // [NB, OUTF]
{
  const int e  = blockIdx.z;
  const int mt = blockIdx.y;
  const int n0 = blockIdx.x * BN;
  const int me = counts[e];
  const int m0 = mt * BM;
  if (m0 >= me) return;              // dead tile — cheap early exit

  __shared__ __align__(16) char smem[4 * ABYTES];  // A0,A1,B0,B1 (64 KiB)
  __shared__ int rid[BM];

  const int t = threadIdx.x;
  if (t < BM) {
    int slot = m0 + t;
    rid[t] = (slot < me) ? rows[e * NB + slot] : -1;
  }
  __syncthreads();

  const int tr = t >> 4;            // staging row-in-group 0..15
  const int tc = t & 15;            // staging float4 col   0..15
  const int w  = t >> 6;
  const int l  = t & 63;
  const int wm = (w >> 1) * 64;     // wave M origin in tile
  const int wn = (w & 1) * 64;      // wave N origin in tile
  const int lr = l & 15;
  const int lk = l >> 4;

  const float* Wb0 = W0 + (size_t)e * OUTF * INF;
  const float* Wb1 = W1 + (size_t)e * OUTF * INF;

  // cache gathered row ids for the 8 A-rows this thread stages
  int rcache[8];
#pragma unroll
  for (int p = 0; p < 8; ++p) rcache[p] = rid[p * 16 + tr];

  f32x4 acc[4][4] = {};

  float4 ra[8], rw[8];              // prefetch registers (f32)

  auto gload = [&](int s) {
    const int k0 = s * BK;
    const bool hi = (k0 >= INF);
    const float* xs = hi ? X1 : X0;
    const float* ws = hi ? Wb1 : Wb0;
    const int kc = (hi ? k0 - INF : k0) + tc * 4;
#pragma unroll
    for (int p = 0; p < 8; ++p) {
      const int row = p * 16 + tr;
      const int r = rcache[p];
      if (r >= 0) ra[p] = *(const float4*)(xs + (size_t)r * INF + kc);
      else        ra[p] = make_float4(0.f, 0.f, 0.f, 0.f);
      rw[p] = *(const float4*)(ws + (size_t)(n0 + row) * INF + kc);
    }
  };

  auto swrite = [&](int buf) {
    char* ab = smem + buf * ABYTES;
    char* bb = smem + 2 * ABYTES + buf * ABYTES;
    const int c0 = tc * 8;          // byte col within 128 B row
#pragma unroll
    for (int p = 0; p < 8; ++p) {
      const int row = p * 16 + tr;
      const int off = row * (BK * 2) + (c0 ^ ((row & 7) << 4));  // XOR swizzle
      ushort4 ha, hw;
      ha.x = f2bf(ra[p].x); ha.y = f2bf(ra[p].y);
      ha.z = f2bf(ra[p].z); ha.w = f2bf(ra[p].w);
      hw.x = f2bf(rw[p].x); hw.y = f2bf(rw[p].y);
      hw.z = f2bf(rw[p].z); hw.w = f2bf(rw[p].w);
      *(ushort4*)(ab + off) = ha;
      *(ushort4*)(bb + off) = hw;
    }
  };

  auto compute = [&](int buf) {
    const char* ab = smem + buf * ABYTES;
    const char* bb = smem + 2 * ABYTES + buf * ABYTES;
#pragma unroll
    for (int kk = 0; kk < 2; ++kk) {
      const int kb = kk * 64 + lk * 16;   // byte col of this lane's 8 bf16
      bf16x8 af[4], bv[4];
#pragma unroll
      for (int f = 0; f < 4; ++f) {
        const int arow = wm + f * 16 + lr;
        af[f] = *(const bf16x8*)(ab + arow * (BK * 2) + (kb ^ ((arow & 7) << 4)));
        const int brow = wn + f * 16 + lr;
        bv[f] = *(const bf16x8*)(bb + brow * (BK * 2) + (kb ^ ((brow & 7) << 4)));
      }
#pragma unroll
      for (int fm = 0; fm < 4; ++fm)
#pragma unroll
        for (int fn = 0; fn < 4; ++fn)
          acc[fm][fn] = __builtin_amdgcn_mfma_f32_16x16x32_bf16(
              af[fm], bv[fn], acc[fm][fn], 0, 0, 0);
    }
  };

  // prologue
  gload(0);
  swrite(0);
  __syncthreads();

  int cur = 0;
  for (int s = 0; s < NSTEP; ++s) {
    if (s + 1 < NSTEP) gload(s + 1);   // issue next-tile global loads early
    compute(cur);                      // ds_read + MFMA on current buffer
    if (s + 1 < NSTEP) swrite(cur ^ 1);// convert + ds_write into other buffer
    __syncthreads();
    cur ^= 1;
  }

  // epilogue: bias + scatter store (scales are both 1.0)
#pragma unroll
  for (int fn = 0; fn < 4; ++fn) {
    const int gcol = n0 + wn + fn * 16 + lr;
    const float bias = B0[e * OUTF + gcol] + B1[e * OUTF + gcol];
#pragma unroll
    for (int fm = 0; fm < 4; ++fm) {
#pragma unroll
      for (int j = 0; j < 4; ++j) {
        const int sl = wm + fm * 16 + lk * 4 + j;   // slot in tile
        const int r = rid[sl];
        if (r >= 0) out[(size_t)r * OUTF + gcol] = acc[fm][fn][j] + bias;
      }
    }
  }
}

extern "C" void kernel_launch(void* const* d_in, const int* in_sizes, int n_in,
                              void* d_out, int out_size, void* d_ws, size_t ws_size,
                              hipStream_t stream) {
  const float* logits = (const float*)d_in[0];
  const float* prior  = (const float*)d_in[1];
  const float* W      = (const float*)d_in[2];
  const float* b      = (const float*)d_in[3];
  const float* Wp     = (const float*)d_in[4];
  const float* bp     = (const float*)d_in[5];
  const int*   eidx   = (const int*)d_in[6];
  float* out = (float*)d_out;

  int* counts = (int*)d_ws;
  int* rows   = counts + 32;   // 128 B pad; rows needs NE*NB*4 = 256 KiB

  hipLaunchKernelGGL(route_init_kernel, dim3(1), dim3(64), 0, stream, counts);
  hipLaunchKernelGGL(route_kernel, dim3(NB / 256), dim3(256), 0, stream,
                     eidx, counts, rows);

  dim3 grid(OUTF / BN, MAXMT, NE);
  hipLaunchKernelGGL(ens_gemm_kernel, grid, dim3(256), 0, stream,
                     logits, prior, W, b, Wp, bp, counts, rows, out);
}